// Round 1
// baseline (7458.252 us; speedup 1.0000x reference)
//
#include <hip/hip_runtime.h>

// Farthest Point Sampling: B=16, N=65536, S=2048. Out: (B, S, 3) fp32.
//
// Round-4 design: XCD-local synchronization.
//  - Grid remap g -> (b = 2*(g&7) + ((g>>3)&1), r = g>>4): under the measured
//    round-robin dispatch (blk % 8 -> XCD), all 16 blocks of a batch land on
//    ONE XCD (2 batches x 16 blocks = 32 CUs = 1 XCD). Verified at runtime by
//    a HW_REG_XCC_ID vote; any mismatch -> agent-scope (L3) fallback path.
//  - Per-WAVE publish (64 slots/batch/parity) from a single fused u64 DPP
//    max chain: key = valbits<<32 | (65535-idx)<<16 | seq. Lexicographic
//    (value, smallest-idx) == round-3's two-chain tie-break, bit-identical.
//  - Fast path: slot stores stay agent-scope (they pass THROUGH the local L2,
//    updating it); polls are sc0-only loads (bypass L1, hit shared L2,
//    ~200cy) with an agent-scope (L3) load every 4th trip after 16 as a
//    liveness backstop. Stale reads can never false-match (exact seq tags;
//    same-parity staleness is always want-2k), so correctness never depends
//    on sc0 semantics. No RMW polling -> no dirty remote-L2 lines.
//  - Fast path has ZERO __syncthreads in the main loop: all 4 waves poll all
//    64 slots and broadcast the winner in-register (ballot+readlane).
//    Fallback keeps wave0-poll + one barrier to cap L3 poll traffic.
//  - Workspace (slots + vote table) zeroed each launch via hipMemsetAsync.
//
// Numerics identical to round 3 / numpy: no FMA, ((dx*dx+dy*dy)+dz*dz),
// fminf, global first-occurrence argmax.

typedef unsigned long long u64;

#define BATCHES 16
#define NPTS    65536
#define NSAMP   2048
#define PB      16                    // blocks per batch
#define TPB     256                   // threads per block
#define WPB     (TPB / 64)            // 4 waves per block
#define PPT     (NPTS / (PB * TPB))   // 16 points per thread
#define SLOTS   (PB * WPB)            // 64 slots per batch per parity

#define WS_SLOTS_BYTES (2 * BATCHES * SLOTS * 8)          // 16 KiB
#define WS_TOTAL_BYTES (WS_SLOTS_BYTES + BATCHES * PB * 4) // + 1 KiB vote tab

// DPP ctrl: 0xB1 xor1, 0x4E xor2, 0x141 row_half_mirror, 0x140 row_mirror,
// 0x142 row_bcast15, 0x143 row_bcast31. 6 stages -> lane 63 holds wave max.
template <int CTRL>
__device__ __forceinline__ u64 dppmax_u64(u64 x) {
  unsigned lo = (unsigned)x, hi = (unsigned)(x >> 32);
  unsigned plo = (unsigned)__builtin_amdgcn_update_dpp(0, (int)lo, CTRL, 0xF, 0xF, true);
  unsigned phi = (unsigned)__builtin_amdgcn_update_dpp(0, (int)hi, CTRL, 0xF, 0xF, true);
  u64 pv = ((u64)phi << 32) | plo;
  return pv > x ? pv : x;  // identity 0 safe: real keys are nonzero
}

__device__ __forceinline__ u64 wave_max_u64(u64 k) {
  k = dppmax_u64<0xB1>(k);
  k = dppmax_u64<0x4E>(k);
  k = dppmax_u64<0x141>(k);
  k = dppmax_u64<0x140>(k);
  k = dppmax_u64<0x142>(k);
  k = dppmax_u64<0x143>(k);
  return k;  // lane 63 = max over all 64 lanes
}

__device__ __forceinline__ u64 bcast63_u64(u64 m) {
  unsigned lo = (unsigned)__builtin_amdgcn_readlane((int)(unsigned)m, 63);
  unsigned hi = (unsigned)__builtin_amdgcn_readlane((int)(unsigned)(m >> 32), 63);
  return ((u64)hi << 32) | lo;
}

// sc0-only load: bypasses L1, served by the XCD-shared L2 (not L3).
__device__ __forceinline__ u64 ld_l2(const u64* p) {
  u64 v;
  asm volatile("global_load_dwordx2 %0, %1, off sc0\n\ts_waitcnt vmcnt(0)"
               : "=v"(v)
               : "v"((u64)p)
               : "memory");
  return v;
}

__device__ __forceinline__ u64 ld_agent(const u64* p) {
  return __hip_atomic_load(p, __ATOMIC_RELAXED, __HIP_MEMORY_SCOPE_AGENT);
}

__device__ __forceinline__ float readlane_f(float x, int l) {
  return __int_as_float(__builtin_amdgcn_readlane(__float_as_int(x), l));
}

__global__ __launch_bounds__(TPB) void fps_kernel(
    const float* __restrict__ coords,
    float* __restrict__ out,
    u64* __restrict__ slots,
    unsigned* __restrict__ xcdtab) {
  const int g = blockIdx.x;
  const int b = 2 * (g & 7) + ((g >> 3) & 1);  // batch (XCD-grouped)
  const int r = g >> 4;                        // rank within batch
  const int t = threadIdx.x;
  const int lane = t & 63;
  const int wave = t >> 6;

  const float* __restrict__ cb = coords + (size_t)b * NPTS * 3;
  const int base = r * (TPB * PPT);

  // Register-resident points + closest-distance array.
  float px[PPT], py[PPT], pz[PPT], cl[PPT];
#pragma unroll
  for (int k = 0; k < PPT; ++k) {
    int idx = base + k * TPB + t;
    px[k] = cb[3 * idx + 0];
    py[k] = cb[3 * idx + 1];
    pz[k] = cb[3 * idx + 2];
    cl[k] = __builtin_inff();
  }

  __shared__ float s_x, s_y, s_z;  // fallback path only

  // --- one-time same-XCD vote (agent scope, table zeroed by host memset) ---
  // HW_REG_XCC_ID: s_getreg id=20, offset=0, width=4 -> imm 0x1814.
  unsigned xcc = (unsigned)__builtin_amdgcn_s_getreg(0x1814) & 0xF;
  if (t == 0)
    __hip_atomic_store(&xcdtab[b * PB + r], xcc + 1, __ATOMIC_RELAXED,
                       __HIP_MEMORY_SCOPE_AGENT);
  unsigned ve;
  do {
    ve = __hip_atomic_load(&xcdtab[b * PB + (lane & 15)], __ATOMIC_RELAXED,
                           __HIP_MEMORY_SCOPE_AGENT);
  } while (ve == 0);
  const bool use_l2 = __all((int)(ve == __shfl(ve, 0)));  // batch-uniform

  // Initial selected point: index 0 (matches reference).
  float sx = cb[0], sy = cb[1], sz = cb[2];

  for (int it = 0; it < NSAMP; ++it) {
    // --- distance update + per-thread argmax (ascending k => first occ.) ---
    float bestv = -1.0f;
    int bestk = 0;
#pragma unroll
    for (int k = 0; k < PPT; ++k) {
      float dx = __fsub_rn(sx, px[k]);
      float dy = __fsub_rn(sy, py[k]);
      float dz = __fsub_rn(sz, pz[k]);
      float d  = __fadd_rn(__fadd_rn(__fmul_rn(dx, dx), __fmul_rn(dy, dy)),
                           __fmul_rn(dz, dz));
      float c  = fminf(cl[k], d);
      cl[k] = c;
      if (c > bestv) { bestv = c; bestk = k; }
    }
    const int bestidx = base + bestk * TPB + t;

    // Fused key: value (monotonic bits, d>=0) | inverted idx | seq space.
    u64 key = ((u64)__float_as_uint(bestv) << 32) |
              ((u64)(unsigned)(65535 - bestidx) << 16);
    key = wave_max_u64(key);

    const int p = (it + 1) & 1;  // parity double-buffer
    u64* bs = slots + (size_t)(p * BATCHES + b) * SLOTS;
    const u64 want = (u64)(unsigned)(it + 1);

    // --- per-wave publish straight from lane 63 (no LDS, no barrier) ---
    if (lane == 63)
      __hip_atomic_store(bs + (r * WPB + wave), key | want, __ATOMIC_RELAXED,
                         __HIP_MEMORY_SCOPE_AGENT);
    asm volatile("" ::: "memory");  // keep publish above the poll loop

    if (use_l2) {
      // ---- FAST PATH: all 4 waves poll all 64 slots via the shared L2 ----
      u64 sv;
      int trip = 0;
      for (;;) {
        if (trip >= 16 && (trip & 3) == 3)
          sv = ld_agent(bs + lane);   // L3 liveness backstop
        else
          sv = ld_l2(bs + lane);      // XCD-local L2 (~200cy)
        if ((sv & 0xFFFFull) == want) break;
        ++trip;
      }
      // Prefetch this slot's candidate coords; hidden behind the reduce.
      int ci = 65535 - (int)((sv >> 16) & 0xFFFFull);
      float gx = cb[3 * ci + 0];
      float gy = cb[3 * ci + 1];
      float gz = cb[3 * ci + 2];

      u64 m = bcast63_u64(wave_max_u64(sv));
      // Winner slot unique (disjoint idx ranges -> unique inv_idx).
      unsigned long long tied = __ballot(sv == m);
      int wl = (int)__ffsll(tied) - 1;  // uniform
      sx = readlane_f(gx, wl);
      sy = readlane_f(gy, wl);
      sz = readlane_f(gz, wl);
      if (r == 0 && wave == 0 && sv == m) {
        float* op = out + ((size_t)b * NSAMP + it) * 3;
        op[0] = gx; op[1] = gy; op[2] = gz;
      }
    } else {
      // ---- FALLBACK: wave0 polls via L3 (2-deep pipelined), LDS bcast ----
      if (wave == 0) {
        u64 a = ld_agent(bs + lane);
        u64 b2 = ld_agent(bs + lane);
        u64 sv;
        for (;;) {
          if ((a & 0xFFFFull) == want) { sv = a; break; }
          a = ld_agent(bs + lane);
          if ((b2 & 0xFFFFull) == want) { sv = b2; break; }
          b2 = ld_agent(bs + lane);
        }
        int ci = 65535 - (int)((sv >> 16) & 0xFFFFull);
        float gx = cb[3 * ci + 0];
        float gy = cb[3 * ci + 1];
        float gz = cb[3 * ci + 2];
        u64 m = bcast63_u64(wave_max_u64(sv));
        if (sv == m) {
          s_x = gx; s_y = gy; s_z = gz;
          if (r == 0) {
            float* op = out + ((size_t)b * NSAMP + it) * 3;
            op[0] = gx; op[1] = gy; op[2] = gz;
          }
        }
      }
      __syncthreads();
      sx = s_x; sy = s_y; sz = s_z;
    }
  }
}

extern "C" void kernel_launch(void* const* d_in, const int* in_sizes, int n_in,
                              void* d_out, int out_size, void* d_ws,
                              size_t ws_size, hipStream_t stream) {
  const float* coords = (const float*)d_in[0];  // (16, 65536, 3) fp32
  // d_in[1] (features) unused by the reference output.
  float* out = (float*)d_out;                   // (16, 2048, 3) fp32
  u64* slots = (u64*)d_ws;                      // 16 KiB
  unsigned* xcdtab = (unsigned*)((char*)d_ws + WS_SLOTS_BYTES);  // 1 KiB
  hipMemsetAsync(d_ws, 0, WS_TOTAL_BYTES, stream);
  fps_kernel<<<dim3(BATCHES * PB), dim3(TPB), 0, stream>>>(coords, out, slots,
                                                           xcdtab);
}

// Round 2
// 5820.647 us; speedup vs baseline: 1.2813x; 1.2813x over previous
//
#include <hip/hip_runtime.h>

// Farthest Point Sampling: B=16, N=65536, S=2048. Out: (B, S, 3) fp32.
//
// Round-5 design: round-3's proven L3 handshake + trimmed critical path.
//
// MEASURED LESSON (round-4 post-mortem): agent-scope slot stores write
// through past L2 to HBM (WRITE_SIZE = #stores x 32B, exactly), so a peer
// CU's store leaves NO readable update in the XCD-shared L2 -> sc0 L2
// polling spins on stale lines forever. L3 (agent scope) is the ONLY
// cross-block mailbox. All polls here are agent-scope.
//
// Per-round structure (one L3 round trip, ONE barrier):
//  - Fused u64 key = valbits<<32 | (65535-idx)<<16 | seq; one 6-stage DPP
//    max chain per wave (lexicographic (value, smallest-idx) == numpy
//    first-occurrence argmax, bit-identical to round 3's two chains).
//  - Per-WAVE publish straight from lane 63 (64 slots/batch/parity): no LDS
//    wave-reduce, no pre-publish barrier, no serial t0 reduce -> slot
//    visible ~300-400 cy earlier than round 3.
//  - Wave 0 polls all 64 slots (one lane each, agent scope) with a 2-deep
//    rotated load pair (two outstanding -> detection quantization ~halved).
//    Exact seq tags can never false-match (same-parity staleness is always
//    want-2k); parity double-buffer prevents cross-round clobber.
//  - Winner broadcast in-register for wave 0 (ballot + readlane); waves 1-3
//    get it via parity-double-buffered LDS + the single __syncthreads.
//
// Numerics identical to rounds 1-3 / numpy: no FMA, ((dx*dx+dy*dy)+dz*dz),
// fminf, global first-occurrence argmax. absmax must stay 0.0.

typedef unsigned long long u64;

#define BATCHES 16
#define NPTS    65536
#define NSAMP   2048
#define PB      16                    // blocks per batch
#define TPB     256                   // threads per block
#define WPB     (TPB / 64)            // 4 waves per block
#define PPT     (NPTS / (PB * TPB))   // 16 points per thread
#define SLOTS   (PB * WPB)            // 64 slots per batch per parity

#define WS_BYTES (2 * BATCHES * SLOTS * 8)  // 16 KiB slot space

// DPP ctrl: 0xB1 xor1, 0x4E xor2, 0x141 row_half_mirror, 0x140 row_mirror,
// 0x142 row_bcast15, 0x143 row_bcast31. 6 stages -> lane 63 holds wave max.
// bound_ctrl 0-fill identity is safe: u64 keys are unsigned, 0 <= anything.
template <int CTRL>
__device__ __forceinline__ u64 dppmax_u64(u64 x) {
  unsigned lo = (unsigned)x, hi = (unsigned)(x >> 32);
  unsigned plo = (unsigned)__builtin_amdgcn_update_dpp(0, (int)lo, CTRL, 0xF, 0xF, true);
  unsigned phi = (unsigned)__builtin_amdgcn_update_dpp(0, (int)hi, CTRL, 0xF, 0xF, true);
  u64 pv = ((u64)phi << 32) | plo;
  return pv > x ? pv : x;
}

__device__ __forceinline__ u64 wave_max_u64(u64 k) {
  k = dppmax_u64<0xB1>(k);
  k = dppmax_u64<0x4E>(k);
  k = dppmax_u64<0x141>(k);
  k = dppmax_u64<0x140>(k);
  k = dppmax_u64<0x142>(k);
  k = dppmax_u64<0x143>(k);
  return k;  // lane 63 = max over all 64 lanes
}

__device__ __forceinline__ u64 bcast63_u64(u64 m) {
  unsigned lo = (unsigned)__builtin_amdgcn_readlane((int)(unsigned)m, 63);
  unsigned hi = (unsigned)__builtin_amdgcn_readlane((int)(unsigned)(m >> 32), 63);
  return ((u64)hi << 32) | lo;
}

__device__ __forceinline__ u64 ld_agent(const u64* p) {
  return __hip_atomic_load(p, __ATOMIC_RELAXED, __HIP_MEMORY_SCOPE_AGENT);
}

__device__ __forceinline__ float readlane_f(float x, int l) {
  return __int_as_float(__builtin_amdgcn_readlane(__float_as_int(x), l));
}

__global__ __launch_bounds__(TPB) void fps_kernel(
    const float* __restrict__ coords,
    float* __restrict__ out,
    u64* __restrict__ slots) {
  const int blk  = blockIdx.x;
  const int b    = blk >> 4;    // batch
  const int r    = blk & 15;    // rank within batch
  const int t    = threadIdx.x;
  const int lane = t & 63;
  const int wave = t >> 6;

  const float* __restrict__ cb = coords + (size_t)b * NPTS * 3;
  const int base = r * (TPB * PPT);

  // Register-resident points + closest-distance array.
  float px[PPT], py[PPT], pz[PPT], cl[PPT];
#pragma unroll
  for (int k = 0; k < PPT; ++k) {
    int idx = base + k * TPB + t;
    px[k] = cb[3 * idx + 0];
    py[k] = cb[3 * idx + 1];
    pz[k] = cb[3 * idx + 2];
    cl[k] = __builtin_inff();
  }

  // Parity-double-buffered broadcast cell -> single barrier per round:
  // wave0 writes s_*[p] before the barrier of round `it`; the next write to
  // the same cell (round it+2) is separated by the round-(it+1) barrier,
  // which waves 1-3 only pass after reading s_*[p].
  __shared__ float s_x[2], s_y[2], s_z[2];

  // Initial selected point: index 0 (matches reference).
  float sx = cb[0], sy = cb[1], sz = cb[2];

  for (int it = 0; it < NSAMP; ++it) {
    // --- distance update + per-thread argmax (ascending k => first occ.) ---
    float bestv = -1.0f;
    int bestk = 0;
#pragma unroll
    for (int k = 0; k < PPT; ++k) {
      float dx = __fsub_rn(sx, px[k]);
      float dy = __fsub_rn(sy, py[k]);
      float dz = __fsub_rn(sz, pz[k]);
      float d  = __fadd_rn(__fadd_rn(__fmul_rn(dx, dx), __fmul_rn(dy, dy)),
                           __fmul_rn(dz, dz));
      float c  = fminf(cl[k], d);
      cl[k] = c;
      if (c > bestv) { bestv = c; bestk = k; }
    }
    const int bestidx = base + bestk * TPB + t;

    // Fused key: value (monotonic bits, d>=0) | inverted idx | seq space.
    u64 key = ((u64)__float_as_uint(bestv) << 32) |
              ((u64)(unsigned)(65535 - bestidx) << 16);
    key = wave_max_u64(key);

    const int p = (it + 1) & 1;  // parity double-buffer
    u64* bs = slots + (size_t)(p * BATCHES + b) * SLOTS;
    const u64 want = (u64)(unsigned)(it + 1);

    // --- per-wave publish straight from lane 63 (no LDS, no barrier) ---
    if (lane == 63)
      __hip_atomic_store(bs + (r * WPB + wave), key | want, __ATOMIC_RELAXED,
                         __HIP_MEMORY_SCOPE_AGENT);
    asm volatile("" ::: "memory");  // keep publish above the poll loop

    float nx = 0.0f, ny = 0.0f, nz = 0.0f;
    if (wave == 0) {
      // ---- wave 0: poll all 64 slots via L3, 2-deep rotated loads ----
      const u64* sp = bs + lane;
      u64 a0 = ld_agent(sp);
      u64 a1 = ld_agent(sp);
      u64 sv;
      for (;;) {
        if ((a0 & 0xFFFFull) == want) { sv = a0; break; }
        a0 = ld_agent(sp);
        if ((a1 & 0xFFFFull) == want) { sv = a1; break; }
        a1 = ld_agent(sp);
      }
      // Prefetch this slot's candidate coords; mostly hidden by the reduce.
      int ci = 65535 - (int)((sv >> 16) & 0xFFFFull);
      float gx = cb[3 * ci + 0];
      float gy = cb[3 * ci + 1];
      float gz = cb[3 * ci + 2];

      u64 m = bcast63_u64(wave_max_u64(sv));
      // Winner slot unique: disjoint idx ranges -> unique (val, inv_idx).
      unsigned long long tied = __ballot(sv == m);
      int wl = (int)__ffsll(tied) - 1;  // uniform winner lane
      nx = readlane_f(gx, wl);
      ny = readlane_f(gy, wl);
      nz = readlane_f(gz, wl);
      if (lane == 0) { s_x[p] = nx; s_y[p] = ny; s_z[p] = nz; }
      if (r == 0 && sv == m) {
        float* op = out + ((size_t)b * NSAMP + it) * 3;
        op[0] = gx; op[1] = gy; op[2] = gz;
      }
    }
    __syncthreads();
    if (wave == 0) { sx = nx; sy = ny; sz = nz; }       // in-register
    else { sx = s_x[p]; sy = s_y[p]; sz = s_z[p]; }     // via LDS
  }
}

extern "C" void kernel_launch(void* const* d_in, const int* in_sizes, int n_in,
                              void* d_out, int out_size, void* d_ws,
                              size_t ws_size, hipStream_t stream) {
  const float* coords = (const float*)d_in[0];  // (16, 65536, 3) fp32
  // d_in[1] (features) unused by the reference output.
  float* out = (float*)d_out;                   // (16, 2048, 3) fp32
  u64* slots = (u64*)d_ws;                      // 16 KiB
  hipMemsetAsync(d_ws, 0, WS_BYTES, stream);    // seq tags start at 0 != 1
  fps_kernel<<<dim3(BATCHES * PB), dim3(TPB), 0, stream>>>(coords, out, slots);
}

// Round 3
// 5009.950 us; speedup vs baseline: 1.4887x; 1.1618x over previous
//
#include <hip/hip_runtime.h>

// Farthest Point Sampling: B=16, N=65536, S=2048. Out: (B, S, 3) fp32.
//
// Round-6 design: round-3's MEASURED-BEST geometry (16 slots / 2 lines per
// batch, t0 block-publish, 16 poller lanes) kept exactly; only intra-block
// latency shaved.
//
// MEASURED LESSONS:
//  - r4: agent stores write through to HBM (WRITE_SIZE = #stores x 32B);
//    peer L2 never sees them -> L3 is the only cross-block mailbox.
//  - r3 FETCH (~1.2 lines/block-round) shows polls are served by L3/MALL,
//    not HBM; handshake cost = L3 latency, not bandwidth.
//  - r5: growing the mailbox to 64 slots / 8 lines / 64 pollers regressed
//    2300cy/round. Slot geometry is contention-sensitive: keep it minimal.
//
// Deltas vs round-3 (geometry-preserving, mechanism-local):
//  1. Fused u64 key = valbits<<32 | (65535-idx)<<16 (low16 = seq space):
//     ONE 6-stage DPP chain replaces the f32 chain + u32 tie-break chain.
//     Lexicographic (value, smallest-idx) == numpy first-occurrence argmax,
//     bit-identical to r1-r5.
//  2. Barriers -> seq-tagged LDS spins (parity double-buffered cells):
//     wave w's lane63 writes its key then tag (payload->lgkmcnt(0)->tag);
//     t0 spin-gathers the 4 tags and publishes immediately; all threads
//     spin on a tagged winner cell instead of barrier #2. Same-parity cell
//     reuse is separated by a full all-block handshake (round +2), and
//     tags are exact-match (stale = want-2), so no torn/stale reads.
//  3. 3-deep rotated poll on the SAME 16 slots: detection quantum ~L3lat/3.
//
// Numerics identical to r1-r5 / numpy: no FMA, ((dx*dx+dy*dy)+dz*dz),
// fminf, global first-occurrence argmax. absmax must stay 0.0.

typedef unsigned long long u64;

#define BATCHES 16
#define NPTS    65536
#define NSAMP   2048
#define PB      16                    // blocks per batch
#define TPB     256                   // threads per block
#define WPB     (TPB / 64)            // 4 waves per block
#define PPT     (NPTS / (PB * TPB))   // 16 points per thread

#define WS_BYTES (2 * BATCHES * PB * 8)  // 4 KiB slot space (parity x b x r)

// DPP ctrl: 0xB1 xor1, 0x4E xor2, 0x141 row_half_mirror, 0x140 row_mirror,
// 0x142 row_bcast15, 0x143 row_bcast31.
// bound_ctrl 0-fill is a safe identity for unsigned max.
template <int CTRL>
__device__ __forceinline__ u64 dppmax_u64(u64 x) {
  unsigned lo = (unsigned)x, hi = (unsigned)(x >> 32);
  unsigned plo = (unsigned)__builtin_amdgcn_update_dpp(0, (int)lo, CTRL, 0xF, 0xF, true);
  unsigned phi = (unsigned)__builtin_amdgcn_update_dpp(0, (int)hi, CTRL, 0xF, 0xF, true);
  u64 pv = ((u64)phi << 32) | plo;
  return pv > x ? pv : x;
}

__device__ __forceinline__ u64 ld_agent(const u64* p) {
  return __hip_atomic_load(p, __ATOMIC_RELAXED, __HIP_MEMORY_SCOPE_AGENT);
}

__global__ __launch_bounds__(TPB) void fps_kernel(
    const float* __restrict__ coords,
    float* __restrict__ out,
    u64* __restrict__ slots) {
  const int blk  = blockIdx.x;
  const int b    = blk >> 4;    // batch
  const int r    = blk & 15;    // rank within batch
  const int t    = threadIdx.x;
  const int lane = t & 63;
  const int wave = t >> 6;

  const float* __restrict__ cb = coords + (size_t)b * NPTS * 3;
  const int base = r * (TPB * PPT);

  // Register-resident points + closest-distance array.
  float px[PPT], py[PPT], pz[PPT], cl[PPT];
#pragma unroll
  for (int k = 0; k < PPT; ++k) {
    int idx = base + k * TPB + t;
    px[k] = cb[3 * idx + 0];
    py[k] = cb[3 * idx + 1];
    pz[k] = cb[3 * idx + 2];
    cl[k] = __builtin_inff();
  }

  // Parity-indexed spin cells. Same-parity reuse is at round it+2, which is
  // gated by the round it+1 handshake (all blocks + all waves), so no
  // overwrite can race a reader. Tags exact-match (stale tag = want-2).
  __shared__ u64      s_wkey[2][WPB];   // per-wave keys
  __shared__ unsigned s_wtag[2][WPB];   // per-wave seq tags
  __shared__ unsigned s_win[2][4];      // {xbits, ybits, zbits, seq}

  if (t == 0) {
#pragma unroll
    for (int q = 0; q < 2; ++q) {
#pragma unroll
      for (int w = 0; w < WPB; ++w) ((volatile unsigned*)s_wtag[q])[w] = 0u;
      ((volatile unsigned*)s_win[q])[3] = 0u;
    }
  }
  __syncthreads();  // one-time init barrier (outside the main loop)

  // Initial selected point: index 0 (matches reference).
  float sx = cb[0], sy = cb[1], sz = cb[2];

  for (int it = 0; it < NSAMP; ++it) {
    // --- distance update + per-thread argmax (ascending k => first occ.) ---
    float bestv = -1.0f;
    int bestk = 0;
#pragma unroll
    for (int k = 0; k < PPT; ++k) {
      float dx = __fsub_rn(sx, px[k]);
      float dy = __fsub_rn(sy, py[k]);
      float dz = __fsub_rn(sz, pz[k]);
      float d  = __fadd_rn(__fadd_rn(__fmul_rn(dx, dx), __fmul_rn(dy, dy)),
                           __fmul_rn(dz, dz));
      float c  = fminf(cl[k], d);
      cl[k] = c;
      if (c > bestv) { bestv = c; bestk = k; }
    }
    const int bestidx = base + bestk * TPB + t;

    const int p = (it + 1) & 1;            // parity
    const unsigned want32 = (unsigned)(it + 1);
    const u64 want = (u64)want32;
    u64* bs = slots + (size_t)(p * BATCHES + b) * PB;

    // --- fused wave reduce: ONE 6-stage u64 DPP chain, lane63 = wave max ---
    u64 key = ((u64)__float_as_uint(bestv) << 32) |
              ((u64)(unsigned)(65535 - bestidx) << 16);
    key = dppmax_u64<0xB1>(key);
    key = dppmax_u64<0x4E>(key);
    key = dppmax_u64<0x141>(key);
    key = dppmax_u64<0x140>(key);
    key = dppmax_u64<0x142>(key);
    key = dppmax_u64<0x143>(key);

    if (lane == 63) {
      *(volatile u64*)&s_wkey[p][wave] = key;               // payload
      asm volatile("s_waitcnt lgkmcnt(0)" ::: "memory");    // order
      ((volatile unsigned*)s_wtag[p])[wave] = want32;       // then tag
    }

    // --- t0: spin-gather the 4 wave tags, reduce, publish (no barrier) ---
    if (t == 0) {
      volatile unsigned* wt = (volatile unsigned*)s_wtag[p];
      unsigned w0, w1, w2, w3;
      do {
        w0 = wt[0]; w1 = wt[1]; w2 = wt[2]; w3 = wt[3];
      } while (w0 != want32 || w1 != want32 || w2 != want32 || w3 != want32);
      u64 bk = *(volatile u64*)&s_wkey[p][0];
#pragma unroll
      for (int w = 1; w < WPB; ++w) {
        u64 o = *(volatile u64*)&s_wkey[p][w];
        if (o > bk) bk = o;
      }
      __hip_atomic_store(bs + r, bk | want, __ATOMIC_RELAXED,
                         __HIP_MEMORY_SCOPE_AGENT);
    }
    asm volatile("" ::: "memory");  // keep publish above the poll loop

    // --- wave0 lanes 0-15: 3-deep rotated poll on the 16 slots (2 lines) ---
    if (wave == 0 && lane < PB) {
      const u64* sp = bs + lane;
      u64 a0 = ld_agent(sp);
      u64 a1 = ld_agent(sp);
      u64 a2 = ld_agent(sp);
      u64 sv;
      for (;;) {
        if ((a0 & 0xFFFFull) == want) { sv = a0; break; }
        a0 = ld_agent(sp);
        if ((a1 & 0xFFFFull) == want) { sv = a1; break; }
        a1 = ld_agent(sp);
        if ((a2 & 0xFFFFull) == want) { sv = a2; break; }
        a2 = ld_agent(sp);
      }
      // Prefetch this slot's candidate coords; overlapped with the reduce.
      int ci = 65535 - (int)((sv >> 16) & 0xFFFFull);
      float gx = cb[3 * ci + 0];
      float gy = cb[3 * ci + 1];
      float gz = cb[3 * ci + 2];

      // 16-lane slot reduce: 4 DPP stages within row 0.
      u64 m = sv;
      m = dppmax_u64<0xB1>(m);
      m = dppmax_u64<0x4E>(m);
      m = dppmax_u64<0x141>(m);
      m = dppmax_u64<0x140>(m);

      // Winner lane unique (disjoint idx ranges -> unique inv_idx).
      if (sv == m) {
        volatile unsigned* wn = (volatile unsigned*)s_win[p];
        wn[0] = __float_as_uint(gx);
        wn[1] = __float_as_uint(gy);
        wn[2] = __float_as_uint(gz);
        asm volatile("s_waitcnt lgkmcnt(0)" ::: "memory");  // payload first
        wn[3] = want32;                                     // then tag
        if (r == 0) {
          float* op = out + ((size_t)b * NSAMP + it) * 3;
          op[0] = gx; op[1] = gy; op[2] = gz;
        }
      }
    }

    // --- all threads: spin on the tagged winner cell (replaces barrier) ---
    {
      volatile unsigned* wn = (volatile unsigned*)s_win[p];
      while (wn[3] != want32) { }
      sx = __uint_as_float(wn[0]);
      sy = __uint_as_float(wn[1]);
      sz = __uint_as_float(wn[2]);
    }
  }
}

extern "C" void kernel_launch(void* const* d_in, const int* in_sizes, int n_in,
                              void* d_out, int out_size, void* d_ws,
                              size_t ws_size, hipStream_t stream) {
  const float* coords = (const float*)d_in[0];  // (16, 65536, 3) fp32
  // d_in[1] (features) unused by the reference output.
  float* out = (float*)d_out;                   // (16, 2048, 3) fp32
  u64* slots = (u64*)d_ws;                      // 4 KiB
  hipMemsetAsync(d_ws, 0, WS_BYTES, stream);    // seq tags start at 0 != 1
  fps_kernel<<<dim3(BATCHES * PB), dim3(TPB), 0, stream>>>(coords, out, slots);
}

// Round 4
// 3804.070 us; speedup vs baseline: 1.9606x; 1.3170x over previous
//
#include <hip/hip_runtime.h>

// Farthest Point Sampling: B=16, N=65536, S=2048. Out: (B, S, 3) fp32.
//
// Round-7 design: round-3's measured-best backbone (16 slots / 2 lines per
// batch, t0 block-publish, 16 poller lanes, BOTH hardware barriers) with the
// serial L3 poll replaced by a genuinely pipelined 4-deep asm poll.
//
// MEASURED LESSONS:
//  - r4: agent stores write through to HBM (WRITE_SIZE = #stores x 32B);
//    peer L2 never sees them -> L3 is the only cross-block mailbox.
//  - r5: growing the mailbox (64 slots / 8 lines / 64 pollers) regressed
//    2300 cy/round. Keep poller x slot geometry minimal.
//  - r6: LDS tag-spins are WORSE than __syncthreads (+600 cy/round): LDS
//    read latency quantizes detection, volatile gathers serialize. Keep HW
//    barriers. ALSO: same-address rotated atomic loads in HIP do NOT
//    pipeline -- FETCH stayed flat, compiler drains vmcnt(0) per check.
//    Hence the poll loop below is inline asm with counted vmcnt(3).
//  - Fused u64 key chain (val<<32 | inv<<16 | seq) is bit-exact vs the
//    separate f32+u32 chains: HW-verified absmax 0.0 in r5 and r6.
//
// Numerics identical to r1-r6 / numpy: no FMA, ((dx*dx+dy*dy)+dz*dz),
// fminf, global first-occurrence argmax. absmax must stay 0.0.

typedef unsigned long long u64;

#define BATCHES 16
#define NPTS    65536
#define NSAMP   2048
#define PB      16                    // blocks per batch
#define TPB     256                   // threads per block
#define WPB     (TPB / 64)            // 4 waves per block
#define PPT     (NPTS / (PB * TPB))   // 16 points per thread

#define WS_BYTES (2 * BATCHES * PB * 8)  // 4 KiB slot space (parity x b x r)

// DPP ctrl: 0xB1 xor1, 0x4E xor2, 0x141 row_half_mirror, 0x140 row_mirror,
// 0x142 row_bcast15, 0x143 row_bcast31.
// bound_ctrl 0-fill is a safe identity for unsigned max.
template <int CTRL>
__device__ __forceinline__ u64 dppmax_u64(u64 x) {
  unsigned lo = (unsigned)x, hi = (unsigned)(x >> 32);
  unsigned plo = (unsigned)__builtin_amdgcn_update_dpp(0, (int)lo, CTRL, 0xF, 0xF, true);
  unsigned phi = (unsigned)__builtin_amdgcn_update_dpp(0, (int)hi, CTRL, 0xF, 0xF, true);
  u64 pv = ((u64)phi << 32) | plo;
  return pv > x ? pv : x;
}

// 4-deep pipelined L3 poll (wave-uniform exit). Four same-address loads kept
// in flight, rotated; counted s_waitcnt vmcnt(3) so a fresh sample retires
// every ~RTT/4 instead of every ~RTT (the HIP compiler refuses to do this:
// r6 showed same-address atomic loads get vmcnt(0)-drained per check).
// Exit: all active lanes' current sample has (lo & 0xffff) == want.
// Result is copied to v[41:42] (never a load target) BEFORE the vmcnt(0)
// drain, so late-landing stale loads cannot clobber it. sc0 sc1 = system
// scope: strict superset of the (working) agent-scope bypass.
__device__ __forceinline__ u64 poll4(const u64* sp, unsigned want32) {
  unsigned lo, hi;
  asm volatile(
      "global_load_dwordx2 v[32:33], %2, off sc0 sc1\n\t"
      "global_load_dwordx2 v[34:35], %2, off sc0 sc1\n\t"
      "global_load_dwordx2 v[36:37], %2, off sc0 sc1\n\t"
      "global_load_dwordx2 v[38:39], %2, off sc0 sc1\n\t"
      "P%=:\n\t"
      "s_waitcnt vmcnt(3)\n\t"
      "v_and_b32 v40, 0xffff, v32\n\t"
      "v_cmp_eq_u32 vcc, %3, v40\n\t"
      "s_andn2_b64 s[20:21], exec, vcc\n\t"
      "s_cbranch_scc0 G0%=\n\t"
      "global_load_dwordx2 v[32:33], %2, off sc0 sc1\n\t"
      "s_waitcnt vmcnt(3)\n\t"
      "v_and_b32 v40, 0xffff, v34\n\t"
      "v_cmp_eq_u32 vcc, %3, v40\n\t"
      "s_andn2_b64 s[20:21], exec, vcc\n\t"
      "s_cbranch_scc0 G1%=\n\t"
      "global_load_dwordx2 v[34:35], %2, off sc0 sc1\n\t"
      "s_waitcnt vmcnt(3)\n\t"
      "v_and_b32 v40, 0xffff, v36\n\t"
      "v_cmp_eq_u32 vcc, %3, v40\n\t"
      "s_andn2_b64 s[20:21], exec, vcc\n\t"
      "s_cbranch_scc0 G2%=\n\t"
      "global_load_dwordx2 v[36:37], %2, off sc0 sc1\n\t"
      "s_waitcnt vmcnt(3)\n\t"
      "v_and_b32 v40, 0xffff, v38\n\t"
      "v_cmp_eq_u32 vcc, %3, v40\n\t"
      "s_andn2_b64 s[20:21], exec, vcc\n\t"
      "s_cbranch_scc0 G3%=\n\t"
      "global_load_dwordx2 v[38:39], %2, off sc0 sc1\n\t"
      "s_branch P%=\n\t"
      "G1%=:\n\t"  // pending loads target v32,v36,v38 -> v34 copy is safe
      "v_mov_b32 v41, v34\n\t"
      "v_mov_b32 v42, v35\n\t"
      "s_branch GD%=\n\t"
      "G2%=:\n\t"  // pending: v32,v34,v38
      "v_mov_b32 v41, v36\n\t"
      "v_mov_b32 v42, v37\n\t"
      "s_branch GD%=\n\t"
      "G3%=:\n\t"  // pending: v32,v34,v36
      "v_mov_b32 v41, v38\n\t"
      "v_mov_b32 v42, v39\n\t"
      "s_branch GD%=\n\t"
      "G0%=:\n\t"  // pending: v34,v36,v38
      "v_mov_b32 v41, v32\n\t"
      "v_mov_b32 v42, v33\n\t"
      "GD%=:\n\t"
      "s_waitcnt vmcnt(0)\n\t"  // drain stale in-flight loads
      "v_mov_b32 %0, v41\n\t"
      "v_mov_b32 %1, v42\n\t"
      : "=v"(lo), "=v"(hi)
      : "v"(sp), "s"(want32)
      : "memory", "vcc", "scc", "v32", "v33", "v34", "v35", "v36", "v37",
        "v38", "v39", "v40", "v41", "v42", "s20", "s21");
  return ((u64)hi << 32) | lo;
}

__global__ __launch_bounds__(TPB) void fps_kernel(
    const float* __restrict__ coords,
    float* __restrict__ out,
    u64* __restrict__ slots) {
  const int blk  = blockIdx.x;
  const int b    = blk >> 4;    // batch
  const int r    = blk & 15;    // rank within batch
  const int t    = threadIdx.x;
  const int lane = t & 63;
  const int wave = t >> 6;

  const float* __restrict__ cb = coords + (size_t)b * NPTS * 3;
  const int base = r * (TPB * PPT);

  // Register-resident points + closest-distance array.
  float px[PPT], py[PPT], pz[PPT], cl[PPT];
#pragma unroll
  for (int k = 0; k < PPT; ++k) {
    int idx = base + k * TPB + t;
    px[k] = cb[3 * idx + 0];
    py[k] = cb[3 * idx + 1];
    pz[k] = cb[3 * idx + 2];
    cl[k] = __builtin_inff();
  }

  __shared__ u64 s_wred[WPB];
  __shared__ float s_x, s_y, s_z;

  // Initial selected point: index 0 (matches reference).
  float sx = cb[0], sy = cb[1], sz = cb[2];

  for (int it = 0; it < NSAMP; ++it) {
    // --- distance update + per-thread argmax (ascending k => first occ.) ---
    float bestv = -1.0f;
    int bestk = 0;
#pragma unroll
    for (int k = 0; k < PPT; ++k) {
      float dx = __fsub_rn(sx, px[k]);
      float dy = __fsub_rn(sy, py[k]);
      float dz = __fsub_rn(sz, pz[k]);
      float d  = __fadd_rn(__fadd_rn(__fmul_rn(dx, dx), __fmul_rn(dy, dy)),
                           __fmul_rn(dz, dz));
      float c  = fminf(cl[k], d);
      cl[k] = c;
      if (c > bestv) { bestv = c; bestk = k; }
    }
    const int bestidx = base + bestk * TPB + t;

    // --- fused wave reduce: ONE 6-stage u64 DPP chain, lane63 = wave max
    // (bit-exact vs separate f32+u32 chains; HW-verified r5/r6) ---
    u64 key = ((u64)__float_as_uint(bestv) << 32) |
              ((u64)(unsigned)(65535 - bestidx) << 16);
    key = dppmax_u64<0xB1>(key);
    key = dppmax_u64<0x4E>(key);
    key = dppmax_u64<0x141>(key);
    key = dppmax_u64<0x140>(key);
    key = dppmax_u64<0x142>(key);
    key = dppmax_u64<0x143>(key);

    if (lane == 63) s_wred[wave] = key;
    __syncthreads();  // barrier #1 (HW barrier: r6 proved spins are worse)

    const int p = (it + 1) & 1;            // parity double-buffer
    const unsigned want32 = (unsigned)(it + 1);
    const u64 want = (u64)want32;
    u64* bs = slots + (size_t)(p * BATCHES + b) * PB;

    // --- t0: reduce the 4 wave keys, publish (val32 | inv16 | seq16) ---
    if (t == 0) {
      u64 bk = s_wred[0];
#pragma unroll
      for (int w = 1; w < WPB; ++w) {
        u64 o = s_wred[w];
        if (o > bk) bk = o;
      }
      __hip_atomic_store(bs + r, bk | want, __ATOMIC_RELAXED,
                         __HIP_MEMORY_SCOPE_AGENT);
    }
    asm volatile("" ::: "memory");  // keep publish above the poll

    // --- wave 0, lanes 0-15: pipelined poll, prefetch coords, DPP-reduce ---
    if (wave == 0 && lane < PB) {
      u64 sv = poll4(bs + lane, want32);

      // Prefetch this slot's candidate coords; overlapped with the reduce.
      int ci = 65535 - (int)((sv >> 16) & 0xFFFFull);
      float gx = cb[3 * ci + 0];
      float gy = cb[3 * ci + 1];
      float gz = cb[3 * ci + 2];

      // 16-lane slot reduce: 4 DPP stages within the row (r1/r3-proven).
      u64 m = sv;
      m = dppmax_u64<0xB1>(m);
      m = dppmax_u64<0x4E>(m);
      m = dppmax_u64<0x141>(m);
      m = dppmax_u64<0x140>(m);

      // Winner lane unique (disjoint idx ranges -> unique inv_idx).
      if (sv == m) {
        s_x = gx; s_y = gy; s_z = gz;
        if (r == 0) {
          float* op = out + ((size_t)b * NSAMP + it) * 3;
          op[0] = gx; op[1] = gy; op[2] = gz;
        }
      }
    }
    __syncthreads();  // barrier #2
    sx = s_x; sy = s_y; sz = s_z;
  }
}

extern "C" void kernel_launch(void* const* d_in, const int* in_sizes, int n_in,
                              void* d_out, int out_size, void* d_ws,
                              size_t ws_size, hipStream_t stream) {
  const float* coords = (const float*)d_in[0];  // (16, 65536, 3) fp32
  // d_in[1] (features) unused by the reference output.
  float* out = (float*)d_out;                   // (16, 2048, 3) fp32
  u64* slots = (u64*)d_ws;                      // 4 KiB
  hipMemsetAsync(d_ws, 0, WS_BYTES, stream);    // seq tags start at 0 != 1
  fps_kernel<<<dim3(BATCHES * PB), dim3(TPB), 0, stream>>>(coords, out, slots);
}